// Round 1
// baseline (226.179 us; speedup 1.0000x reference)
//
#include <hip/hip_runtime.h>

#define Rtot 65536
#define Wimg 256
#define Himg 256
#define Kp 64
#define NSTEPS 64
#define DTc (1.0f/256.0f)
#define INV_VOLR (1.0f/256.0f)

// prim data layout (16 floats per prim):
// [0..2] pos_n, [3..5] per-axis cull radius, [6..14] rsc[i][j]=rot[i][j]*scale[j], [15] pad
__global__ __launch_bounds__(64) void prep_kernel(
    const float* __restrict__ primpos, const float* __restrict__ primrot,
    const float* __restrict__ primscale, float* __restrict__ pd) {
  int k = threadIdx.x;
  if (k >= Kp) return;
  float sc0 = primscale[k*3+0], sc1 = primscale[k*3+1], sc2 = primscale[k*3+2];
  float rot[9];
#pragma unroll
  for (int i = 0; i < 9; ++i) rot[i] = primrot[k*9+i];
  float* o = pd + (k << 4);
  o[0] = primpos[k*3+0] * INV_VOLR;
  o[1] = primpos[k*3+1] * INV_VOLR;
  o[2] = primpos[k*3+2] * INV_VOLR;
#pragma unroll
  for (int i = 0; i < 3; ++i) {
    o[3+i] = fabsf(rot[i*3+0])/sc0 + fabsf(rot[i*3+1])/sc1 + fabsf(rot[i*3+2])/sc2;
  }
#pragma unroll
  for (int i = 0; i < 3; ++i) {
    o[6+i*3+0] = rot[i*3+0]*sc0;
    o[6+i*3+1] = rot[i*3+1]*sc1;
    o[6+i*3+2] = rot[i*3+2]*sc2;
  }
  o[15] = 0.0f;
}

__device__ __forceinline__ void accum_prim(const float* __restrict__ p,
                                           const float* __restrict__ tmpl,
                                           int k, float px, float py, float pz,
                                           float c[4]) {
  float relx = px - p[0], rely = py - p[1], relz = pz - p[2];
  // local_j = sum_i rel_i * rot[i][j] * scale[j]  (rsc folded)
  float lx = relx*p[6]  + rely*p[9]  + relz*p[12];
  float ly = relx*p[7]  + rely*p[10] + relz*p[13];
  float lz = relx*p[8]  + rely*p[11] + relz*p[14];
  if (!(fabsf(lx) < 1.0f && fabsf(ly) < 1.0f && fabsf(lz) < 1.0f)) return;
  float gx = fminf(fmaxf((lx + 1.0f)*7.5f, 0.0f), 14.99999f);
  float gy = fminf(fmaxf((ly + 1.0f)*7.5f, 0.0f), 14.99999f);
  float gz = fminf(fmaxf((lz + 1.0f)*7.5f, 0.0f), 14.99999f);
  int ix = (int)gx, iy = (int)gy, iz = (int)gz;
  ix = ix > 14 ? 14 : ix;  iy = iy > 14 ? 14 : iy;  iz = iz > 14 ? 14 : iz;
  float fx = gx - (float)ix, fy = gy - (float)iy, fz = gz - (float)iz;
  float wx0 = 1.0f - fx, wy0 = 1.0f - fy, wz0 = 1.0f - fz;
  float w00 = wz0*wy0, w01 = wz0*fy, w10 = fz*wy0, w11 = fz*fy;
  // template: (K,4,16,16,16); offset = (k*4+ch)*4096 + iz*256 + iy*16 + ix
  const float* base = tmpl + (((size_t)k) << 14) + iz*256 + iy*16 + ix;
#pragma unroll
  for (int ch = 0; ch < 4; ++ch) {
    const float* b = base + ch*4096;
    float a = (b[0]  *wx0 + b[1]  *fx) * w00
            + (b[16] *wx0 + b[17] *fx) * w01
            + (b[256]*wx0 + b[257]*fx) * w10
            + (b[272]*wx0 + b[273]*fx) * w11;
    c[ch] += a;
  }
}

// Phase 1: one block per (16x16 ray tile, step). Cull prims vs. block bbox,
// compute per-ray density s (4ch) for surviving prims, write s-buffer + flag.
__global__ __launch_bounds__(256) void phase1_kernel(
    const float* __restrict__ raypos, const float* __restrict__ raydir,
    const float* __restrict__ tminmax, const float* __restrict__ pd,
    const float* __restrict__ tmpl, float4* __restrict__ sbuf,
    unsigned char* __restrict__ flags) {
  __shared__ float s_red[4][6];
  __shared__ int s_list[Kp];
  __shared__ int s_count;
  int tx = threadIdx.x, ty = threadIdx.y;
  int tid = ty*16 + tx;
  int w = blockIdx.x*16 + tx, h = blockIdx.y*16 + ty;
  int step = blockIdx.z;
  int r = h*Wimg + w;
  float ox = raypos[r*3+0], oy = raypos[r*3+1], oz = raypos[r*3+2];
  float dx = raydir[r*3+0], dy = raydir[r*3+1], dz = raydir[r*3+2];
  float tmin = tminmax[r*2+0];
  float t = tmin + ((float)step + 0.5f)*DTc;
  float px = fmaf(t, dx, ox), py = fmaf(t, dy, oy), pz = fmaf(t, dz, oz);

  // block-wide bbox of sample positions (wave shuffle-reduce, then LDS)
  float mnx=px, mny=py, mnz=pz, mxx=px, mxy=py, mxz=pz;
#pragma unroll
  for (int m = 1; m < 64; m <<= 1) {
    mnx = fminf(mnx, __shfl_xor(mnx, m));
    mny = fminf(mny, __shfl_xor(mny, m));
    mnz = fminf(mnz, __shfl_xor(mnz, m));
    mxx = fmaxf(mxx, __shfl_xor(mxx, m));
    mxy = fmaxf(mxy, __shfl_xor(mxy, m));
    mxz = fmaxf(mxz, __shfl_xor(mxz, m));
  }
  int wv = tid >> 6;
  if ((tid & 63) == 0) {
    s_red[wv][0]=mnx; s_red[wv][1]=mny; s_red[wv][2]=mnz;
    s_red[wv][3]=mxx; s_red[wv][4]=mxy; s_red[wv][5]=mxz;
  }
  __syncthreads();
  if (tid < 64) {
    float bmnx = fminf(fminf(s_red[0][0], s_red[1][0]), fminf(s_red[2][0], s_red[3][0]));
    float bmny = fminf(fminf(s_red[0][1], s_red[1][1]), fminf(s_red[2][1], s_red[3][1]));
    float bmnz = fminf(fminf(s_red[0][2], s_red[1][2]), fminf(s_red[2][2], s_red[3][2]));
    float bmxx = fmaxf(fmaxf(s_red[0][3], s_red[1][3]), fmaxf(s_red[2][3], s_red[3][3]));
    float bmxy = fmaxf(fmaxf(s_red[0][4], s_red[1][4]), fmaxf(s_red[2][4], s_red[3][4]));
    float bmxz = fmaxf(fmaxf(s_red[0][5], s_red[1][5]), fmaxf(s_red[2][5], s_red[3][5]));
    const float* p = pd + (tid << 4);
    bool pass = (p[0] >= bmnx - p[3]) && (p[0] <= bmxx + p[3])
             && (p[1] >= bmny - p[4]) && (p[1] <= bmxy + p[4])
             && (p[2] >= bmnz - p[5]) && (p[2] <= bmxz + p[5]);
    unsigned long long mask = __ballot(pass);
    if (tid == 0) s_count = (int)__popcll(mask);
    if (pass) {
      int pos = (int)__popcll(mask & ((1ull << tid) - 1ull));
      s_list[pos] = tid;
    }
  }
  __syncthreads();
  int cnt = s_count;
  int tileIdx = blockIdx.y*16 + blockIdx.x;
  if (tid == 0) flags[tileIdx*NSTEPS + step] = (unsigned char)(cnt > 0 ? 1 : 0);
  if (cnt == 0) return;

  float c[4] = {0.0f, 0.0f, 0.0f, 0.0f};
  for (int j = 0; j < cnt; ++j) {
    int k = __builtin_amdgcn_readfirstlane(s_list[j]);  // wave-uniform -> scalar loads
    accum_prim(pd + (k << 4), tmpl, k, px, py, pz, c);
  }
  sbuf[(tileIdx*NSTEPS + step)*256 + tid] = make_float4(c[0], c[1], c[2], c[3]);
}

// Phase 2: one thread per ray; sequential alpha compositing over 64 steps.
__global__ __launch_bounds__(256) void phase2_kernel(
    const float* __restrict__ tminmax, const float4* __restrict__ sbuf,
    const unsigned char* __restrict__ flags, float* __restrict__ out) {
  __shared__ unsigned char s_flags[NSTEPS];
  int tid = threadIdx.x;
  int b = blockIdx.x;
  if (tid < NSTEPS) s_flags[tid] = flags[b*NSTEPS + tid];
  __syncthreads();
  int w = (b & 15)*16 + (tid & 15);
  int h = (b >> 4)*16 + (tid >> 4);
  int r = h*Wimg + w;
  float tmin = tminmax[r*2+0], tmax = tminmax[r*2+1];
  float rgb0=0.0f, rgb1=0.0f, rgb2=0.0f, alpha=0.0f;
  for (int i = 0; i < NSTEPS; ++i) {
    float4 s = make_float4(0.0f, 0.0f, 0.0f, 0.0f);
    if (s_flags[i]) s = sbuf[(b*NSTEPS + i)*256 + tid];
    float t = tmin + ((float)i + 0.5f)*DTc;
    float contrib = fminf(1.0f, fmaf(s.w, DTc, alpha)) - alpha;
    contrib = (t < tmax) ? contrib : 0.0f;
    rgb0 = fmaf(s.x, contrib, rgb0);
    rgb1 = fmaf(s.y, contrib, rgb1);
    rgb2 = fmaf(s.z, contrib, rgb2);
    alpha += contrib;
  }
  // outputs: rgb(3 planes), alpha(1), rgba(4)
  out[0*Rtot + r] = rgb0;
  out[1*Rtot + r] = rgb1;
  out[2*Rtot + r] = rgb2;
  out[3*Rtot + r] = alpha;
  out[4*Rtot + r] = rgb0;
  out[5*Rtot + r] = rgb1;
  out[6*Rtot + r] = rgb2;
  out[7*Rtot + r] = alpha;
}

// Self-contained fallback (no workspace): one thread per ray, all prims.
__global__ __launch_bounds__(256) void fallback_kernel(
    const float* __restrict__ raypos, const float* __restrict__ raydir,
    const float* __restrict__ tminmax,
    const float* __restrict__ primpos, const float* __restrict__ primrot,
    const float* __restrict__ primscale, const float* __restrict__ tmpl,
    float* __restrict__ out) {
  __shared__ float s_pd[Kp][16];
  int tx = threadIdx.x, ty = threadIdx.y;
  int tid = ty*16 + tx;
  if (tid < Kp) {
    int k = tid;
    float sc0 = primscale[k*3+0], sc1 = primscale[k*3+1], sc2 = primscale[k*3+2];
    s_pd[k][0] = primpos[k*3+0]*INV_VOLR;
    s_pd[k][1] = primpos[k*3+1]*INV_VOLR;
    s_pd[k][2] = primpos[k*3+2]*INV_VOLR;
    s_pd[k][3] = 0.0f; s_pd[k][4] = 0.0f; s_pd[k][5] = 0.0f;
#pragma unroll
    for (int i = 0; i < 3; ++i) {
      s_pd[k][6+i*3+0] = primrot[k*9+i*3+0]*sc0;
      s_pd[k][6+i*3+1] = primrot[k*9+i*3+1]*sc1;
      s_pd[k][6+i*3+2] = primrot[k*9+i*3+2]*sc2;
    }
  }
  __syncthreads();
  int w = blockIdx.x*16 + tx, h = blockIdx.y*16 + ty;
  int r = h*Wimg + w;
  float ox = raypos[r*3+0], oy = raypos[r*3+1], oz = raypos[r*3+2];
  float dx = raydir[r*3+0], dy = raydir[r*3+1], dz = raydir[r*3+2];
  float tmin = tminmax[r*2+0], tmax = tminmax[r*2+1];
  float rgb0=0.0f, rgb1=0.0f, rgb2=0.0f, alpha=0.0f;
  for (int i = 0; i < NSTEPS; ++i) {
    float t = tmin + ((float)i + 0.5f)*DTc;
    float px = fmaf(t, dx, ox), py = fmaf(t, dy, oy), pz = fmaf(t, dz, oz);
    float c[4] = {0.0f, 0.0f, 0.0f, 0.0f};
    for (int k = 0; k < Kp; ++k) accum_prim(&s_pd[k][0], tmpl, k, px, py, pz, c);
    float contrib = fminf(1.0f, fmaf(c[3], DTc, alpha)) - alpha;
    contrib = (t < tmax) ? contrib : 0.0f;
    rgb0 = fmaf(c[0], contrib, rgb0);
    rgb1 = fmaf(c[1], contrib, rgb1);
    rgb2 = fmaf(c[2], contrib, rgb2);
    alpha += contrib;
  }
  out[0*Rtot + r] = rgb0;
  out[1*Rtot + r] = rgb1;
  out[2*Rtot + r] = rgb2;
  out[3*Rtot + r] = alpha;
  out[4*Rtot + r] = rgb0;
  out[5*Rtot + r] = rgb1;
  out[6*Rtot + r] = rgb2;
  out[7*Rtot + r] = alpha;
}

extern "C" void kernel_launch(void* const* d_in, const int* in_sizes, int n_in,
                              void* d_out, int out_size, void* d_ws, size_t ws_size,
                              hipStream_t stream) {
  const float* raypos    = (const float*)d_in[0];
  const float* raydir    = (const float*)d_in[1];
  const float* tminmax   = (const float*)d_in[2];
  const float* primpos   = (const float*)d_in[3];
  const float* primrot   = (const float*)d_in[4];
  const float* primscale = (const float*)d_in[5];
  const float* primrgba  = (const float*)d_in[6];
  float* out = (float*)d_out;

  const size_t FLAG_OFF = 4096;                       // prim data: 64*16*4 = 4 KB
  const size_t SBUF_OFF = 4096 + 16384;               // flags: 256 tiles * 64 steps
  const size_t NEED = SBUF_OFF + (size_t)256*64*256*16;  // s-buffer: 67.1 MB

  if (ws_size >= NEED) {
    float* pd = (float*)d_ws;
    unsigned char* flags = (unsigned char*)d_ws + FLAG_OFF;
    float4* sbuf = (float4*)((char*)d_ws + SBUF_OFF);
    prep_kernel<<<1, 64, 0, stream>>>(primpos, primrot, primscale, pd);
    phase1_kernel<<<dim3(16,16,64), dim3(16,16), 0, stream>>>(
        raypos, raydir, tminmax, pd, primrgba, sbuf, flags);
    phase2_kernel<<<256, 256, 0, stream>>>(tminmax, sbuf, flags, out);
  } else {
    fallback_kernel<<<dim3(16,16), dim3(16,16), 0, stream>>>(
        raypos, raydir, tminmax, primpos, primrot, primscale, primrgba, out);
  }
}

// Round 2
// 105.486 us; speedup vs baseline: 2.1442x; 2.1442x over previous
//
#include <hip/hip_runtime.h>
#include <hip/hip_fp16.h>

#define Rtot 65536
#define Wimg 256
#define Kp 64
#define NSTEPS 64
#define DTc (1.0f/256.0f)
#define INV_VOLR (1.0f/256.0f)
#define NITEMS 16384
#define HOTGRID 2048

// ws layout (bytes)
#define PD_OFF    0u          // 64 prims * 16 floats = 4 KB
#define QC_OFF    4096u       // queue counter (16 B)
#define TB_OFF    8192u       // 256 tiles * 16 floats = 16 KB
#define FLAG_OFF  24576u      // 16384 bytes
#define LIST_OFF  65536u      // 16384 * 64 bytes = 1 MB
#define QUEUE_OFF 1114112u    // 16384 * 4 = 64 KB
#define TT_OFF    2097152u    // transposed template: 64*4096*16 B = 4 MB
#define SBUF_OFF  8388608u    // fp16 s-buffer: 16384*256*8 B = 33.5 MB
#define WS_NEED   (SBUF_OFF + (size_t)NITEMS*256*8)

// prim data layout (16 floats per prim):
// [0..2] pos_n, [3..5] per-axis cull radius, [6..14] rsc[i][j]=rot[i][j]*scale[j]
__global__ __launch_bounds__(64) void prep_kernel(
    const float* __restrict__ primpos, const float* __restrict__ primrot,
    const float* __restrict__ primscale, float* __restrict__ pd, int* __restrict__ qc) {
  int k = threadIdx.x;
  if (k == 0) qc[0] = 0;
  if (k >= Kp) return;
  float sc0 = primscale[k*3+0], sc1 = primscale[k*3+1], sc2 = primscale[k*3+2];
  float rot[9];
#pragma unroll
  for (int i = 0; i < 9; ++i) rot[i] = primrot[k*9+i];
  float* o = pd + (k << 4);
  o[0] = primpos[k*3+0] * INV_VOLR;
  o[1] = primpos[k*3+1] * INV_VOLR;
  o[2] = primpos[k*3+2] * INV_VOLR;
#pragma unroll
  for (int i = 0; i < 3; ++i)
    o[3+i] = fabsf(rot[i*3+0])/sc0 + fabsf(rot[i*3+1])/sc1 + fabsf(rot[i*3+2])/sc2;
#pragma unroll
  for (int i = 0; i < 3; ++i) {
    o[6+i*3+0] = rot[i*3+0]*sc0;
    o[6+i*3+1] = rot[i*3+1]*sc1;
    o[6+i*3+2] = rot[i*3+2]*sc2;
  }
  o[15] = 0.0f;
}

// Transpose template (K,4,16,16,16) -> (K,16^3) of float4 (channels innermost).
__global__ __launch_bounds__(256) void transpose_kernel(
    const float* __restrict__ tmpl, float4* __restrict__ tt) {
  int k = blockIdx.x;
  const float* b0 = tmpl + (((size_t)k) << 14);
  float4* o = tt + (k << 12);
  for (int v = threadIdx.x; v < 4096; v += 256)
    o[v] = make_float4(b0[v], b0[4096+v], b0[8192+v], b0[12288+v]);
}

// Per-tile bounds of ray origin, dir, tmin (7 mins, 7 maxs).
__global__ __launch_bounds__(256) void tilebbox_kernel(
    const float* __restrict__ raypos, const float* __restrict__ raydir,
    const float* __restrict__ tminmax, float* __restrict__ tb) {
  __shared__ float smn[4][7], smx[4][7];
  int b = blockIdx.x, tid = threadIdx.x;
  int w = (b & 15)*16 + (tid & 15);
  int h = (b >> 4)*16 + (tid >> 4);
  int r = h*Wimg + w;
  float v[7];
  v[0] = raypos[r*3+0]; v[1] = raypos[r*3+1]; v[2] = raypos[r*3+2];
  v[3] = raydir[r*3+0]; v[4] = raydir[r*3+1]; v[5] = raydir[r*3+2];
  v[6] = tminmax[r*2+0];
  float mn[7], mx[7];
#pragma unroll
  for (int i = 0; i < 7; ++i) { mn[i] = v[i]; mx[i] = v[i]; }
#pragma unroll
  for (int m = 1; m < 64; m <<= 1) {
#pragma unroll
    for (int i = 0; i < 7; ++i) {
      mn[i] = fminf(mn[i], __shfl_xor(mn[i], m));
      mx[i] = fmaxf(mx[i], __shfl_xor(mx[i], m));
    }
  }
  int wv = tid >> 6;
  if ((tid & 63) == 0) {
#pragma unroll
    for (int i = 0; i < 7; ++i) { smn[wv][i] = mn[i]; smx[wv][i] = mx[i]; }
  }
  __syncthreads();
  if (tid == 0) {
#pragma unroll
    for (int i = 0; i < 7; ++i) {
      tb[b*16 + i]     = fminf(fminf(smn[0][i], smn[1][i]), fminf(smn[2][i], smn[3][i]));
      tb[b*16 + 8 + i] = fmaxf(fmaxf(smx[0][i], smx[1][i]), fmaxf(smx[2][i], smx[3][i]));
    }
  }
}

// Cull: 4 items per block (one per wave). Conservative interval-arith bbox.
__global__ __launch_bounds__(256) void cull_kernel(
    const float* __restrict__ pd, const float* __restrict__ tb,
    unsigned char* __restrict__ flags, unsigned char* __restrict__ lists,
    int* __restrict__ queue, int* __restrict__ qc) {
  int wv = threadIdx.x >> 6, lane = threadIdx.x & 63;
  int item = blockIdx.x*4 + wv;
  int tile = item >> 6, step = item & 63;
  const float* t0 = tb + tile*16;
  float tl = t0[6]  + ((float)step + 0.5f)*DTc;
  float th = t0[14] + ((float)step + 0.5f)*DTc;
  float lo[3], hi[3];
#pragma unroll
  for (int a = 0; a < 3; ++a) {
    float ol = t0[a], oh = t0[8+a], dl = t0[3+a], dh = t0[11+a];
    float p1 = tl*dl, p2 = tl*dh, p3 = th*dl, p4 = th*dh;
    lo[a] = ol + fminf(fminf(p1, p2), fminf(p3, p4));
    hi[a] = oh + fmaxf(fmaxf(p1, p2), fmaxf(p3, p4));
  }
  const float* p = pd + (lane << 4);
  bool pass = (p[0] >= lo[0]-p[3]) && (p[0] <= hi[0]+p[3])
           && (p[1] >= lo[1]-p[4]) && (p[1] <= hi[1]+p[4])
           && (p[2] >= lo[2]-p[5]) && (p[2] <= hi[2]+p[5]);
  unsigned long long mask = __ballot(pass);
  int cnt = (int)__popcll(mask);
  if (lane == 0) flags[item] = (unsigned char)(cnt > 0 ? 1 : 0);
  if (pass) {
    int pos = (int)__popcll(mask & ((1ull << lane) - 1ull));
    lists[item*64 + pos] = (unsigned char)lane;
  }
  if (cnt > 0 && lane == 0) {
    int qpos = atomicAdd(qc, 1);
    queue[qpos] = item | (cnt << 16);
  }
}

// Hot shading: fixed grid, grid-stride over queue items. One thread per ray.
__global__ __launch_bounds__(256) void hot_kernel(
    const float* __restrict__ raypos, const float* __restrict__ raydir,
    const float* __restrict__ tminmax, const float* __restrict__ pd,
    const float4* __restrict__ tt, const unsigned char* __restrict__ lists,
    const int* __restrict__ queue, const int* __restrict__ qc,
    uint2* __restrict__ sbuf) {
  __shared__ int s_list[Kp];
  int qn = qc[0];
  int tid = threadIdx.x;
  for (int it = blockIdx.x; it < qn; it += HOTGRID) {
    int entry = queue[it];
    int item = entry & 0xFFFF;
    int cnt = entry >> 16;
    int tile = item >> 6, step = item & 63;
    __syncthreads();
    if (tid < cnt) s_list[tid] = lists[item*64 + tid];
    __syncthreads();
    int w = (tile & 15)*16 + (tid & 15);
    int h = (tile >> 4)*16 + (tid >> 4);
    int r = h*Wimg + w;
    float t = tminmax[r*2] + ((float)step + 0.5f)*DTc;
    float px = fmaf(t, raydir[r*3+0], raypos[r*3+0]);
    float py = fmaf(t, raydir[r*3+1], raypos[r*3+1]);
    float pz = fmaf(t, raydir[r*3+2], raypos[r*3+2]);
    float c0 = 0.f, c1 = 0.f, c2 = 0.f, c3 = 0.f;
    for (int j = 0; j < cnt; ++j) {
      int k = __builtin_amdgcn_readfirstlane(s_list[j]);
      const float* p = pd + (k << 4);
      float relx = px - p[0], rely = py - p[1], relz = pz - p[2];
      float lx = relx*p[6] + rely*p[9]  + relz*p[12];
      float ly = relx*p[7] + rely*p[10] + relz*p[13];
      float lz = relx*p[8] + rely*p[11] + relz*p[14];
      if (fabsf(lx) < 1.0f && fabsf(ly) < 1.0f && fabsf(lz) < 1.0f) {
        float gx = fminf(fmaxf((lx + 1.0f)*7.5f, 0.0f), 14.99999f);
        float gy = fminf(fmaxf((ly + 1.0f)*7.5f, 0.0f), 14.99999f);
        float gz = fminf(fmaxf((lz + 1.0f)*7.5f, 0.0f), 14.99999f);
        int ix = (int)gx, iy = (int)gy, iz = (int)gz;
        ix = ix > 14 ? 14 : ix; iy = iy > 14 ? 14 : iy; iz = iz > 14 ? 14 : iz;
        float fx = gx - (float)ix, fy = gy - (float)iy, fz = gz - (float)iz;
        float wx0 = 1.0f - fx, wy0 = 1.0f - fy, wz0 = 1.0f - fz;
        float w00 = wz0*wy0, w01 = wz0*fy, w10 = fz*wy0, w11 = fz*fy;
        const float4* tbase = tt + (k << 12) + iz*256 + iy*16 + ix;
        float4 a00 = tbase[0],   a01 = tbase[1];
        float4 a10 = tbase[16],  a11 = tbase[17];
        float4 a20 = tbase[256], a21 = tbase[257];
        float4 a30 = tbase[272], a31 = tbase[273];
        c0 += (a00.x*wx0 + a01.x*fx)*w00 + (a10.x*wx0 + a11.x*fx)*w01
            + (a20.x*wx0 + a21.x*fx)*w10 + (a30.x*wx0 + a31.x*fx)*w11;
        c1 += (a00.y*wx0 + a01.y*fx)*w00 + (a10.y*wx0 + a11.y*fx)*w01
            + (a20.y*wx0 + a21.y*fx)*w10 + (a30.y*wx0 + a31.y*fx)*w11;
        c2 += (a00.z*wx0 + a01.z*fx)*w00 + (a10.z*wx0 + a11.z*fx)*w01
            + (a20.z*wx0 + a21.z*fx)*w10 + (a30.z*wx0 + a31.z*fx)*w11;
        c3 += (a00.w*wx0 + a01.w*fx)*w00 + (a10.w*wx0 + a11.w*fx)*w01
            + (a20.w*wx0 + a21.w*fx)*w10 + (a30.w*wx0 + a31.w*fx)*w11;
      }
    }
    __half2 lo2 = __floats2half2_rn(c0, c1);
    __half2 hi2 = __floats2half2_rn(c2, c3);
    sbuf[item*256 + tid] = make_uint2(*(unsigned int*)&lo2, *(unsigned int*)&hi2);
  }
}

// Composite: one thread per ray, sequential over 64 steps.
__global__ __launch_bounds__(256) void phase2_kernel(
    const float* __restrict__ tminmax, const uint2* __restrict__ sbuf,
    const unsigned char* __restrict__ flags, float* __restrict__ out) {
  __shared__ unsigned char s_flags[NSTEPS];
  int tid = threadIdx.x;
  int b = blockIdx.x;
  if (tid < NSTEPS) s_flags[tid] = flags[b*NSTEPS + tid];
  __syncthreads();
  int w = (b & 15)*16 + (tid & 15);
  int h = (b >> 4)*16 + (tid >> 4);
  int r = h*Wimg + w;
  float tmin = tminmax[r*2+0], tmax = tminmax[r*2+1];
  float rgb0 = 0.f, rgb1 = 0.f, rgb2 = 0.f, alpha = 0.f;
  for (int i = 0; i < NSTEPS; ++i) {
    float s0 = 0.f, s1 = 0.f, s2 = 0.f, s3 = 0.f;
    if (s_flags[i]) {
      uint2 pk = sbuf[(b*NSTEPS + i)*256 + tid];
      __half2 lo2 = *(__half2*)&pk.x;
      __half2 hi2 = *(__half2*)&pk.y;
      float2 lf = __half22float2(lo2);
      float2 hf = __half22float2(hi2);
      s0 = lf.x; s1 = lf.y; s2 = hf.x; s3 = hf.y;
    }
    float t = tmin + ((float)i + 0.5f)*DTc;
    float contrib = fminf(1.0f, fmaf(s3, DTc, alpha)) - alpha;
    contrib = (t < tmax) ? contrib : 0.0f;
    rgb0 = fmaf(s0, contrib, rgb0);
    rgb1 = fmaf(s1, contrib, rgb1);
    rgb2 = fmaf(s2, contrib, rgb2);
    alpha += contrib;
  }
  out[0*Rtot + r] = rgb0;
  out[1*Rtot + r] = rgb1;
  out[2*Rtot + r] = rgb2;
  out[3*Rtot + r] = alpha;
  out[4*Rtot + r] = rgb0;
  out[5*Rtot + r] = rgb1;
  out[6*Rtot + r] = rgb2;
  out[7*Rtot + r] = alpha;
}

// Self-contained fallback (no workspace): one thread per ray, all prims.
__global__ __launch_bounds__(256) void fallback_kernel(
    const float* __restrict__ raypos, const float* __restrict__ raydir,
    const float* __restrict__ tminmax,
    const float* __restrict__ primpos, const float* __restrict__ primrot,
    const float* __restrict__ primscale, const float* __restrict__ tmpl,
    float* __restrict__ out) {
  __shared__ float s_pd[Kp][16];
  int tx = threadIdx.x, ty = threadIdx.y;
  int tid = ty*16 + tx;
  if (tid < Kp) {
    int k = tid;
    float sc0 = primscale[k*3+0], sc1 = primscale[k*3+1], sc2 = primscale[k*3+2];
    s_pd[k][0] = primpos[k*3+0]*INV_VOLR;
    s_pd[k][1] = primpos[k*3+1]*INV_VOLR;
    s_pd[k][2] = primpos[k*3+2]*INV_VOLR;
#pragma unroll
    for (int i = 0; i < 3; ++i) {
      s_pd[k][6+i*3+0] = primrot[k*9+i*3+0]*sc0;
      s_pd[k][6+i*3+1] = primrot[k*9+i*3+1]*sc1;
      s_pd[k][6+i*3+2] = primrot[k*9+i*3+2]*sc2;
    }
  }
  __syncthreads();
  int w = blockIdx.x*16 + tx, h = blockIdx.y*16 + ty;
  int r = h*Wimg + w;
  float ox = raypos[r*3+0], oy = raypos[r*3+1], oz = raypos[r*3+2];
  float dx = raydir[r*3+0], dy = raydir[r*3+1], dz = raydir[r*3+2];
  float tmin = tminmax[r*2+0], tmax = tminmax[r*2+1];
  float rgb0=0.f, rgb1=0.f, rgb2=0.f, alpha=0.f;
  for (int i = 0; i < NSTEPS; ++i) {
    float t = tmin + ((float)i + 0.5f)*DTc;
    float px = fmaf(t, dx, ox), py = fmaf(t, dy, oy), pz = fmaf(t, dz, oz);
    float c[4] = {0.f, 0.f, 0.f, 0.f};
    for (int k = 0; k < Kp; ++k) {
      const float* p = &s_pd[k][0];
      float relx = px - p[0], rely = py - p[1], relz = pz - p[2];
      float lx = relx*p[6] + rely*p[9]  + relz*p[12];
      float ly = relx*p[7] + rely*p[10] + relz*p[13];
      float lz = relx*p[8] + rely*p[11] + relz*p[14];
      if (!(fabsf(lx) < 1.0f && fabsf(ly) < 1.0f && fabsf(lz) < 1.0f)) continue;
      float gx = fminf(fmaxf((lx + 1.0f)*7.5f, 0.0f), 14.99999f);
      float gy = fminf(fmaxf((ly + 1.0f)*7.5f, 0.0f), 14.99999f);
      float gz = fminf(fmaxf((lz + 1.0f)*7.5f, 0.0f), 14.99999f);
      int ix = (int)gx, iy = (int)gy, iz = (int)gz;
      ix = ix > 14 ? 14 : ix; iy = iy > 14 ? 14 : iy; iz = iz > 14 ? 14 : iz;
      float fx = gx - (float)ix, fy = gy - (float)iy, fz = gz - (float)iz;
      float wx0 = 1.0f - fx, wy0 = 1.0f - fy, wz0 = 1.0f - fz;
      float w00 = wz0*wy0, w01 = wz0*fy, w10 = fz*wy0, w11 = fz*fy;
      const float* base = tmpl + (((size_t)k) << 14) + iz*256 + iy*16 + ix;
#pragma unroll
      for (int ch = 0; ch < 4; ++ch) {
        const float* bb = base + ch*4096;
        c[ch] += (bb[0]  *wx0 + bb[1]  *fx) * w00
               + (bb[16] *wx0 + bb[17] *fx) * w01
               + (bb[256]*wx0 + bb[257]*fx) * w10
               + (bb[272]*wx0 + bb[273]*fx) * w11;
      }
    }
    float contrib = fminf(1.0f, fmaf(c[3], DTc, alpha)) - alpha;
    contrib = (t < tmax) ? contrib : 0.0f;
    rgb0 = fmaf(c[0], contrib, rgb0);
    rgb1 = fmaf(c[1], contrib, rgb1);
    rgb2 = fmaf(c[2], contrib, rgb2);
    alpha += contrib;
  }
  out[0*Rtot + r] = rgb0;
  out[1*Rtot + r] = rgb1;
  out[2*Rtot + r] = rgb2;
  out[3*Rtot + r] = alpha;
  out[4*Rtot + r] = rgb0;
  out[5*Rtot + r] = rgb1;
  out[6*Rtot + r] = rgb2;
  out[7*Rtot + r] = alpha;
}

extern "C" void kernel_launch(void* const* d_in, const int* in_sizes, int n_in,
                              void* d_out, int out_size, void* d_ws, size_t ws_size,
                              hipStream_t stream) {
  const float* raypos    = (const float*)d_in[0];
  const float* raydir    = (const float*)d_in[1];
  const float* tminmax   = (const float*)d_in[2];
  const float* primpos   = (const float*)d_in[3];
  const float* primrot   = (const float*)d_in[4];
  const float* primscale = (const float*)d_in[5];
  const float* primrgba  = (const float*)d_in[6];
  float* out = (float*)d_out;

  if (ws_size >= WS_NEED) {
    char* ws = (char*)d_ws;
    float* pd            = (float*)(ws + PD_OFF);
    int* qc              = (int*)(ws + QC_OFF);
    float* tb            = (float*)(ws + TB_OFF);
    unsigned char* flags = (unsigned char*)(ws + FLAG_OFF);
    unsigned char* lists = (unsigned char*)(ws + LIST_OFF);
    int* queue           = (int*)(ws + QUEUE_OFF);
    float4* tt           = (float4*)(ws + TT_OFF);
    uint2* sbuf          = (uint2*)(ws + SBUF_OFF);

    prep_kernel<<<1, 64, 0, stream>>>(primpos, primrot, primscale, pd, qc);
    transpose_kernel<<<Kp, 256, 0, stream>>>(primrgba, tt);
    tilebbox_kernel<<<256, 256, 0, stream>>>(raypos, raydir, tminmax, tb);
    cull_kernel<<<NITEMS/4, 256, 0, stream>>>(pd, tb, flags, lists, queue, qc);
    hot_kernel<<<HOTGRID, 256, 0, stream>>>(raypos, raydir, tminmax, pd, tt,
                                            lists, queue, qc, sbuf);
    phase2_kernel<<<256, 256, 0, stream>>>(tminmax, sbuf, flags, out);
  } else {
    fallback_kernel<<<dim3(16,16), dim3(16,16), 0, stream>>>(
        raypos, raydir, tminmax, primpos, primrot, primscale, primrgba, out);
  }
}

// Round 3
// 70.375 us; speedup vs baseline: 3.2139x; 1.4989x over previous
//
#include <hip/hip_runtime.h>
#include <hip/hip_fp16.h>

#define Rtot 65536
#define Wimg 256
#define Kp 64
#define NSTEPS 64
#define DTc (1.0f/256.0f)
#define INV_VOLR (1.0f/256.0f)
#define NITEMS 16384

// ws layout (bytes)
#define PD_OFF    0u          // 64 prims * 16 floats = 4 KB
#define TB_OFF    4096u       // 256 tiles * 16 floats = 16 KB
#define TT_OFF    65536u      // fp16 packed template: 64*4096*16 B = 4 MB
#define SBUF_OFF  8388608u    // fp16 s-buffer: 16384*256*8 B = 33.5 MB
#define WS_NEED   (SBUF_OFF + (size_t)NITEMS*256*8)

__device__ __forceinline__ unsigned int pack2(float a, float b) {
  __half2 h = __floats2half2_rn(a, b);
  return *(unsigned int*)&h;
}

// Fused setup:
//  blocks 0..255   : per-tile bounds of ray origin/dir/tmin -> tb
//  blocks 256..319 : repack template (K,4,16,16,16) f32 -> (K,4096) uint4 of
//                    8 fp16 {c0..c3 @ x, c0..c3 @ x+1}  (x+1 clamped)
//  block 320       : prim data (pos_n, rsc[i][j]=rot[i][j]*scale[j])
__global__ __launch_bounds__(256) void setup_kernel(
    const float* __restrict__ raypos, const float* __restrict__ raydir,
    const float* __restrict__ tminmax, const float* __restrict__ primpos,
    const float* __restrict__ primrot, const float* __restrict__ primscale,
    const float* __restrict__ tmpl,
    float* __restrict__ tb, uint4* __restrict__ tth, float* __restrict__ pd) {
  int bid = blockIdx.x, tid = threadIdx.x;
  if (bid < 256) {
    __shared__ float smn[4][7], smx[4][7];
    int w = (bid & 15)*16 + (tid & 15);
    int h = (bid >> 4)*16 + (tid >> 4);
    int r = h*Wimg + w;
    float v[7];
    v[0] = raypos[r*3+0]; v[1] = raypos[r*3+1]; v[2] = raypos[r*3+2];
    v[3] = raydir[r*3+0]; v[4] = raydir[r*3+1]; v[5] = raydir[r*3+2];
    v[6] = tminmax[r*2+0];
    float mn[7], mx[7];
#pragma unroll
    for (int i = 0; i < 7; ++i) { mn[i] = v[i]; mx[i] = v[i]; }
#pragma unroll
    for (int m = 1; m < 64; m <<= 1) {
#pragma unroll
      for (int i = 0; i < 7; ++i) {
        mn[i] = fminf(mn[i], __shfl_xor(mn[i], m));
        mx[i] = fmaxf(mx[i], __shfl_xor(mx[i], m));
      }
    }
    int wv = tid >> 6;
    if ((tid & 63) == 0) {
#pragma unroll
      for (int i = 0; i < 7; ++i) { smn[wv][i] = mn[i]; smx[wv][i] = mx[i]; }
    }
    __syncthreads();
    if (tid == 0) {
#pragma unroll
      for (int i = 0; i < 7; ++i) {
        tb[bid*16 + i]     = fminf(fminf(smn[0][i], smn[1][i]), fminf(smn[2][i], smn[3][i]));
        tb[bid*16 + 8 + i] = fmaxf(fmaxf(smx[0][i], smx[1][i]), fmaxf(smx[2][i], smx[3][i]));
      }
    }
  } else if (bid < 320) {
    int k = bid - 256;
    const float* b0 = tmpl + (((size_t)k) << 14);
    uint4* o = tth + (k << 12);
    for (int v = tid; v < 4096; v += 256) {
      int x = v & 15;
      int xn = (x < 15) ? v + 1 : v;
      uint4 q;
      q.x = pack2(b0[v],       b0[4096+v]);
      q.y = pack2(b0[8192+v],  b0[12288+v]);
      q.z = pack2(b0[xn],      b0[4096+xn]);
      q.w = pack2(b0[8192+xn], b0[12288+xn]);
      o[v] = q;
    }
  } else {
    int k = tid;
    if (k < Kp) {
      float sc0 = primscale[k*3+0], sc1 = primscale[k*3+1], sc2 = primscale[k*3+2];
      float* o = pd + (k << 4);
      o[0] = primpos[k*3+0] * INV_VOLR;
      o[1] = primpos[k*3+1] * INV_VOLR;
      o[2] = primpos[k*3+2] * INV_VOLR;
      o[3] = 0.0f; o[4] = 0.0f; o[5] = 0.0f;
#pragma unroll
      for (int i = 0; i < 3; ++i) {
        o[6+i*3+0] = primrot[k*9+i*3+0]*sc0;
        o[6+i*3+1] = primrot[k*9+i*3+1]*sc1;
        o[6+i*3+2] = primrot[k*9+i*3+2]*sc2;
      }
      o[15] = 0.0f;
    }
  }
}

// Shade: one block per (tile,step). Wave 0 culls prims in PRIM-LOCAL space
// (interval arithmetic); empty blocks exit; survivors shade 256 rays.
__global__ __launch_bounds__(256) void shade_kernel(
    const float* __restrict__ raypos, const float* __restrict__ raydir,
    const float* __restrict__ tminmax, const float* __restrict__ pd,
    const float* __restrict__ tb, const uint4* __restrict__ tth,
    uint2* __restrict__ sbuf) {
  __shared__ int s_list[Kp];
  __shared__ int s_cnt;
  int item = blockIdx.x;
  int tile = item >> 6, step = item & 63;
  int tid = threadIdx.x;
  if (tid < 64) {
    const float* t0 = tb + tile*16;
    float cst = ((float)step + 0.5f)*DTc;
    float tl = t0[6] + cst, th = t0[14] + cst;
    const float* p = pd + (tid << 4);
    float rlo[3], rhi[3];
#pragma unroll
    for (int a = 0; a < 3; ++a) {
      float ol = t0[a], oh = t0[8+a], dl = t0[3+a], dh = t0[11+a];
      float p1 = tl*dl, p2 = tl*dh, p3 = th*dl, p4 = th*dh;
      float lo = ol + fminf(fminf(p1, p2), fminf(p3, p4));
      float hi = oh + fmaxf(fmaxf(p1, p2), fmaxf(p3, p4));
      rlo[a] = lo - p[a];
      rhi[a] = hi - p[a];
    }
    bool pass = true;
#pragma unroll
    for (int j = 0; j < 3; ++j) {
      float llo = 0.f, lhi = 0.f;
#pragma unroll
      for (int a = 0; a < 3; ++a) {
        float rsc = p[6+a*3+j];
        float q1 = rlo[a]*rsc, q2 = rhi[a]*rsc;
        llo += fminf(q1, q2);
        lhi += fmaxf(q1, q2);
      }
      pass = pass && (llo < 1.0f) && (lhi > -1.0f);
    }
    unsigned long long mask = __ballot(pass);
    if (tid == 0) s_cnt = (int)__popcll(mask);
    if (pass) {
      int pos = (int)__popcll(mask & ((1ull << tid) - 1ull));
      s_list[pos] = tid;
    }
  }
  __syncthreads();
  int cnt = s_cnt;
  if (cnt == 0) return;

  int w = (tile & 15)*16 + (tid & 15);
  int h = (tile >> 4)*16 + (tid >> 4);
  int r = h*Wimg + w;
  float t = tminmax[r*2] + ((float)step + 0.5f)*DTc;
  float px = fmaf(t, raydir[r*3+0], raypos[r*3+0]);
  float py = fmaf(t, raydir[r*3+1], raypos[r*3+1]);
  float pz = fmaf(t, raydir[r*3+2], raypos[r*3+2]);
  float c0 = 0.f, c1 = 0.f, c2 = 0.f, c3 = 0.f;
  for (int j = 0; j < cnt; ++j) {
    int k = __builtin_amdgcn_readfirstlane(s_list[j]);
    const float* p = pd + (k << 4);
    float relx = px - p[0], rely = py - p[1], relz = pz - p[2];
    float lx = relx*p[6] + rely*p[9]  + relz*p[12];
    float ly = relx*p[7] + rely*p[10] + relz*p[13];
    float lz = relx*p[8] + rely*p[11] + relz*p[14];
    bool inside = fabsf(lx) < 1.0f && fabsf(ly) < 1.0f && fabsf(lz) < 1.0f;
    if (__any(inside)) {
      if (inside) {
        float gx = fminf(fmaxf((lx + 1.0f)*7.5f, 0.0f), 14.99999f);
        float gy = fminf(fmaxf((ly + 1.0f)*7.5f, 0.0f), 14.99999f);
        float gz = fminf(fmaxf((lz + 1.0f)*7.5f, 0.0f), 14.99999f);
        int ix = (int)gx, iy = (int)gy, iz = (int)gz;
        ix = ix > 14 ? 14 : ix; iy = iy > 14 ? 14 : iy; iz = iz > 14 ? 14 : iz;
        float fx = gx - (float)ix, fy = gy - (float)iy, fz = gz - (float)iz;
        float wx0 = 1.0f - fx, wy0 = 1.0f - fy, wz0 = 1.0f - fz;
        float w00 = wz0*wy0, w01 = wz0*fy, w10 = fz*wy0, w11 = fz*fy;
        const uint4* tb4 = tth + ((size_t)k << 12) + iz*256 + iy*16 + ix;
        uint4 q00 = tb4[0];
        uint4 q01 = tb4[16];
        uint4 q10 = tb4[256];
        uint4 q11 = tb4[272];
#define ACCQ(q, wv) { \
        float2 p01 = __half22float2(*(const __half2*)&q.x); \
        float2 p23 = __half22float2(*(const __half2*)&q.y); \
        float2 n01 = __half22float2(*(const __half2*)&q.z); \
        float2 n23 = __half22float2(*(const __half2*)&q.w); \
        float wa = (wv)*wx0, wb = (wv)*fx; \
        c0 = fmaf(p01.x, wa, fmaf(n01.x, wb, c0)); \
        c1 = fmaf(p01.y, wa, fmaf(n01.y, wb, c1)); \
        c2 = fmaf(p23.x, wa, fmaf(n23.x, wb, c2)); \
        c3 = fmaf(p23.y, wa, fmaf(n23.y, wb, c3)); }
        ACCQ(q00, w00) ACCQ(q01, w01) ACCQ(q10, w10) ACCQ(q11, w11)
#undef ACCQ
      }
    }
  }
  __half2 lo2 = __floats2half2_rn(c0, c1);
  __half2 hi2 = __floats2half2_rn(c2, c3);
  sbuf[item*256 + tid] = make_uint2(*(unsigned int*)&lo2, *(unsigned int*)&hi2);
}

// Composite: one thread per ray; sbuf pre-zeroed so loads are unconditional
// (full 64-deep MLP, no branches).
__global__ __launch_bounds__(256) void composite_kernel(
    const float* __restrict__ tminmax, const uint2* __restrict__ sbuf,
    float* __restrict__ out) {
  int tid = threadIdx.x;
  int b = blockIdx.x;
  int w = (b & 15)*16 + (tid & 15);
  int h = (b >> 4)*16 + (tid >> 4);
  int r = h*Wimg + w;
  float tmin = tminmax[r*2+0], tmax = tminmax[r*2+1];
  float rgb0 = 0.f, rgb1 = 0.f, rgb2 = 0.f, alpha = 0.f;
#pragma unroll
  for (int i = 0; i < NSTEPS; ++i) {
    uint2 pk = sbuf[(b*NSTEPS + i)*256 + tid];
    float2 lf = __half22float2(*(__half2*)&pk.x);
    float2 hf = __half22float2(*(__half2*)&pk.y);
    float t = tmin + ((float)i + 0.5f)*DTc;
    float contrib = fminf(1.0f, fmaf(hf.y, DTc, alpha)) - alpha;
    contrib = (t < tmax) ? contrib : 0.0f;
    rgb0 = fmaf(lf.x, contrib, rgb0);
    rgb1 = fmaf(lf.y, contrib, rgb1);
    rgb2 = fmaf(hf.x, contrib, rgb2);
    alpha += contrib;
  }
  out[0*Rtot + r] = rgb0;
  out[1*Rtot + r] = rgb1;
  out[2*Rtot + r] = rgb2;
  out[3*Rtot + r] = alpha;
  out[4*Rtot + r] = rgb0;
  out[5*Rtot + r] = rgb1;
  out[6*Rtot + r] = rgb2;
  out[7*Rtot + r] = alpha;
}

// Self-contained fallback (no workspace): one thread per ray, all prims.
__global__ __launch_bounds__(256) void fallback_kernel(
    const float* __restrict__ raypos, const float* __restrict__ raydir,
    const float* __restrict__ tminmax,
    const float* __restrict__ primpos, const float* __restrict__ primrot,
    const float* __restrict__ primscale, const float* __restrict__ tmpl,
    float* __restrict__ out) {
  __shared__ float s_pd[Kp][16];
  int tx = threadIdx.x, ty = threadIdx.y;
  int tid = ty*16 + tx;
  if (tid < Kp) {
    int k = tid;
    float sc0 = primscale[k*3+0], sc1 = primscale[k*3+1], sc2 = primscale[k*3+2];
    s_pd[k][0] = primpos[k*3+0]*INV_VOLR;
    s_pd[k][1] = primpos[k*3+1]*INV_VOLR;
    s_pd[k][2] = primpos[k*3+2]*INV_VOLR;
#pragma unroll
    for (int i = 0; i < 3; ++i) {
      s_pd[k][6+i*3+0] = primrot[k*9+i*3+0]*sc0;
      s_pd[k][6+i*3+1] = primrot[k*9+i*3+1]*sc1;
      s_pd[k][6+i*3+2] = primrot[k*9+i*3+2]*sc2;
    }
  }
  __syncthreads();
  int w = blockIdx.x*16 + tx, h = blockIdx.y*16 + ty;
  int r = h*Wimg + w;
  float ox = raypos[r*3+0], oy = raypos[r*3+1], oz = raypos[r*3+2];
  float dx = raydir[r*3+0], dy = raydir[r*3+1], dz = raydir[r*3+2];
  float tmin = tminmax[r*2+0], tmax = tminmax[r*2+1];
  float rgb0=0.f, rgb1=0.f, rgb2=0.f, alpha=0.f;
  for (int i = 0; i < NSTEPS; ++i) {
    float t = tmin + ((float)i + 0.5f)*DTc;
    float px = fmaf(t, dx, ox), py = fmaf(t, dy, oy), pz = fmaf(t, dz, oz);
    float c[4] = {0.f, 0.f, 0.f, 0.f};
    for (int k = 0; k < Kp; ++k) {
      const float* p = &s_pd[k][0];
      float relx = px - p[0], rely = py - p[1], relz = pz - p[2];
      float lx = relx*p[6] + rely*p[9]  + relz*p[12];
      float ly = relx*p[7] + rely*p[10] + relz*p[13];
      float lz = relx*p[8] + rely*p[11] + relz*p[14];
      if (!(fabsf(lx) < 1.0f && fabsf(ly) < 1.0f && fabsf(lz) < 1.0f)) continue;
      float gx = fminf(fmaxf((lx + 1.0f)*7.5f, 0.0f), 14.99999f);
      float gy = fminf(fmaxf((ly + 1.0f)*7.5f, 0.0f), 14.99999f);
      float gz = fminf(fmaxf((lz + 1.0f)*7.5f, 0.0f), 14.99999f);
      int ix = (int)gx, iy = (int)gy, iz = (int)gz;
      ix = ix > 14 ? 14 : ix; iy = iy > 14 ? 14 : iy; iz = iz > 14 ? 14 : iz;
      float fx = gx - (float)ix, fy = gy - (float)iy, fz = gz - (float)iz;
      float wx0 = 1.0f - fx, wy0 = 1.0f - fy, wz0 = 1.0f - fz;
      float w00 = wz0*wy0, w01 = wz0*fy, w10 = fz*wy0, w11 = fz*fy;
      const float* base = tmpl + (((size_t)k) << 14) + iz*256 + iy*16 + ix;
#pragma unroll
      for (int ch = 0; ch < 4; ++ch) {
        const float* bb = base + ch*4096;
        c[ch] += (bb[0]  *wx0 + bb[1]  *fx) * w00
               + (bb[16] *wx0 + bb[17] *fx) * w01
               + (bb[256]*wx0 + bb[257]*fx) * w10
               + (bb[272]*wx0 + bb[273]*fx) * w11;
      }
    }
    float contrib = fminf(1.0f, fmaf(c[3], DTc, alpha)) - alpha;
    contrib = (t < tmax) ? contrib : 0.0f;
    rgb0 = fmaf(c[0], contrib, rgb0);
    rgb1 = fmaf(c[1], contrib, rgb1);
    rgb2 = fmaf(c[2], contrib, rgb2);
    alpha += contrib;
  }
  out[0*Rtot + r] = rgb0;
  out[1*Rtot + r] = rgb1;
  out[2*Rtot + r] = rgb2;
  out[3*Rtot + r] = alpha;
  out[4*Rtot + r] = rgb0;
  out[5*Rtot + r] = rgb1;
  out[6*Rtot + r] = rgb2;
  out[7*Rtot + r] = alpha;
}

extern "C" void kernel_launch(void* const* d_in, const int* in_sizes, int n_in,
                              void* d_out, int out_size, void* d_ws, size_t ws_size,
                              hipStream_t stream) {
  const float* raypos    = (const float*)d_in[0];
  const float* raydir    = (const float*)d_in[1];
  const float* tminmax   = (const float*)d_in[2];
  const float* primpos   = (const float*)d_in[3];
  const float* primrot   = (const float*)d_in[4];
  const float* primscale = (const float*)d_in[5];
  const float* primrgba  = (const float*)d_in[6];
  float* out = (float*)d_out;

  if (ws_size >= WS_NEED) {
    char* ws = (char*)d_ws;
    float* pd   = (float*)(ws + PD_OFF);
    float* tb   = (float*)(ws + TB_OFF);
    uint4* tth  = (uint4*)(ws + TT_OFF);
    uint2* sbuf = (uint2*)(ws + SBUF_OFF);

    hipMemsetAsync(sbuf, 0, (size_t)NITEMS*256*8, stream);
    setup_kernel<<<321, 256, 0, stream>>>(raypos, raydir, tminmax, primpos,
                                          primrot, primscale, primrgba,
                                          tb, tth, pd);
    shade_kernel<<<NITEMS, 256, 0, stream>>>(raypos, raydir, tminmax, pd, tb,
                                             tth, sbuf);
    composite_kernel<<<256, 256, 0, stream>>>(tminmax, sbuf, out);
  } else {
    fallback_kernel<<<dim3(16,16), dim3(16,16), 0, stream>>>(
        raypos, raydir, tminmax, primpos, primrot, primscale, primrgba, out);
  }
}